// Round 1
// baseline (1896.496 us; speedup 1.0000x reference)
//
#include <hip/hip_runtime.h>
#include <math.h>

// Problem constants
#define B_   2
#define S_   2048
#define H_   16
#define D_   64
#define DM_  1024

// d_out layout (float offsets): out | weights | pos_bias
#define W_OFF   (2*2048*1024)              // 4,194,304
#define PB_OFF  (W_OFF + 2*16*2048*2048LL) // 138,412,032

// T5 relative-position bucket, fp32 math ordered like the numpy reference.
__device__ __forceinline__ int rel_bucket(int rel) {
    int ret = rel > 0 ? 32 : 0;
    int n = rel < 0 ? -rel : rel;
    if (n < 16) return ret + n;
    float fn = (float)n;
    float t = logf(fn * (1.0f / 16.0f));   // log(n/16), /16 exact
    t = t / 1.1394343f;                    // fp32(np.log(50/16))
    int large = 16 + (int)(t * 16.0f);     // trunc toward zero (values >= 0)
    if (large > 31) large = 31;
    return ret + large;
}

// C[m][n] = A[m][:] . W[:][n] + bias[n]; M=4096, N=K=1024.
// attn_layout: write to (b, h, s, d) with b=m>>11, s=m&2047, h=n>>6, d=n&63.
__global__ __launch_bounds__(256)
void gemm_4096_1024(const float* __restrict__ A, const float* __restrict__ W,
                    const float* __restrict__ bias, float* __restrict__ C,
                    int attn_layout)
{
    __shared__ float As[16 * 68];   // [k][m], stride 68
    __shared__ float Bs[16 * 68];   // [k][n], stride 68
    const int tid = threadIdx.x;
    const int bm = blockIdx.y * 64;
    const int bn = blockIdx.x * 64;
    const int tx = tid & 15, ty = tid >> 4;
    const int a_row = tid >> 2, a_col = (tid & 3) * 4;
    const int b_row = tid >> 4, b_col = (tid & 15) * 4;

    float acc[4][4] = {};
    for (int k0 = 0; k0 < 1024; k0 += 16) {
        float4 av = *(const float4*)&A[(size_t)(bm + a_row) * 1024 + k0 + a_col];
        float4 bv = *(const float4*)&W[(size_t)(k0 + b_row) * 1024 + bn + b_col];
        __syncthreads();
        As[(a_col + 0) * 68 + a_row] = av.x;
        As[(a_col + 1) * 68 + a_row] = av.y;
        As[(a_col + 2) * 68 + a_row] = av.z;
        As[(a_col + 3) * 68 + a_row] = av.w;
        *(float4*)&Bs[b_row * 68 + b_col] = bv;
        __syncthreads();
        #pragma unroll
        for (int kk = 0; kk < 16; ++kk) {
            float4 a4 = *(const float4*)&As[kk * 68 + ty * 4];
            float4 b4 = *(const float4*)&Bs[kk * 68 + tx * 4];
            float aa[4] = {a4.x, a4.y, a4.z, a4.w};
            float bb[4] = {b4.x, b4.y, b4.z, b4.w};
            #pragma unroll
            for (int i = 0; i < 4; ++i)
                #pragma unroll
                for (int j = 0; j < 4; ++j)
                    acc[i][j] += aa[i] * bb[j];
        }
    }
    float4 bia = *(const float4*)&bias[bn + tx * 4];
    float bi[4] = {bia.x, bia.y, bia.z, bia.w};
    #pragma unroll
    for (int i = 0; i < 4; ++i) {
        int m = bm + ty * 4 + i;
        float4 r = make_float4(acc[i][0] + bi[0], acc[i][1] + bi[1],
                               acc[i][2] + bi[2], acc[i][3] + bi[3]);
        size_t idx;
        if (attn_layout) {
            int b = m >> 11, srow = m & 2047, h = bn >> 6;
            idx = ((size_t)(b * 16 + h) * 2048 + srow) * 64 + (tx * 4);
        } else {
            idx = (size_t)m * 1024 + bn + tx * 4;
        }
        *(float4*)&C[idx] = r;
    }
}

// Attention: per (b,h) and 64-query tile. Pass 1: raw scores (+bias+mask) ->
// weights buffer, online (m,l). Pass 2: normalize in place + AV accumulate.
__global__ __launch_bounds__(256)
void attn_kernel(const float* __restrict__ qg, const float* __restrict__ kg,
                 const float* __restrict__ vg, const float* __restrict__ rel_table,
                 const int* __restrict__ mask, float* __restrict__ wout,
                 float* __restrict__ ctx)
{
    __shared__ float buf1[64 * 68];
    __shared__ float buf2[64 * 68];
    __shared__ float mres[64], lrcp[64];
    __shared__ float relb[64];
    __shared__ float maskf[64];

    const int tid = threadIdx.x;
    const int bh = blockIdx.y;       // b*16 + h
    const int b = bh >> 4, h = bh & 15;
    const int qt0 = blockIdx.x * 64;
    const int tx = tid & 15, ty = tid >> 4;

    if (tid < 64) relb[tid] = rel_table[tid * 16 + h];

    // q tile, transposed: buf1[dd*68 + qrow]
    {
        const float* qbase = qg + ((size_t)bh * 2048 + qt0) * 64;
        #pragma unroll
        for (int r = 0; r < 4; ++r) {
            int s = tid + r * 256;
            int row = s >> 4, dc = (s & 15) * 4;
            float4 v = *(const float4*)&qbase[row * 64 + dc];
            buf1[(dc + 0) * 68 + row] = v.x;
            buf1[(dc + 1) * 68 + row] = v.y;
            buf1[(dc + 2) * 68 + row] = v.z;
            buf1[(dc + 3) * 68 + row] = v.w;
        }
    }

    float m_i[4], l_i[4];
    #pragma unroll
    for (int i = 0; i < 4; ++i) { m_i[i] = -3.0e38f; l_i[i] = 0.0f; }

    float* wbase = wout + (size_t)bh * 2048 * 2048;

    for (int c = 0; c < 32; ++c) {
        __syncthreads();
        const float* kbase = kg + ((size_t)bh * 2048 + c * 64) * 64;
        #pragma unroll
        for (int r = 0; r < 4; ++r) {
            int s = tid + r * 256;
            int row = s >> 4, dc = (s & 15) * 4;
            float4 v = *(const float4*)&kbase[row * 64 + dc];
            buf2[(dc + 0) * 68 + row] = v.x;
            buf2[(dc + 1) * 68 + row] = v.y;
            buf2[(dc + 2) * 68 + row] = v.z;
            buf2[(dc + 3) * 68 + row] = v.w;
        }
        if (tid < 64) maskf[tid] = mask[b * 2048 + c * 64 + tid] ? -1.0e30f : 0.0f;
        __syncthreads();

        float acc[4][4] = {};
        #pragma unroll 8
        for (int dd = 0; dd < 64; ++dd) {
            float4 q4 = *(const float4*)&buf1[dd * 68 + ty * 4];
            float4 k4 = *(const float4*)&buf2[dd * 68 + tx * 4];
            float qa[4] = {q4.x, q4.y, q4.z, q4.w};
            float ka[4] = {k4.x, k4.y, k4.z, k4.w};
            #pragma unroll
            for (int i = 0; i < 4; ++i)
                #pragma unroll
                for (int j = 0; j < 4; ++j)
                    acc[i][j] += qa[i] * ka[j];
        }
        #pragma unroll
        for (int i = 0; i < 4; ++i) {
            int qglob = qt0 + ty * 4 + i;
            float4 sv;
            float* sp = (float*)&sv;
            #pragma unroll
            for (int j = 0; j < 4; ++j) {
                int kloc = tx * 4 + j;
                int kglob = c * 64 + kloc;
                float s = acc[i][j] + relb[rel_bucket(kglob - qglob)] + maskf[kloc];
                sp[j] = s;
                float mn = fmaxf(m_i[i], s);
                l_i[i] = l_i[i] * __expf(m_i[i] - mn) + __expf(s - mn);
                m_i[i] = mn;
            }
            *(float4*)&wbase[(size_t)qglob * 2048 + c * 64 + tx * 4] = sv;
        }
    }

    // reduce (m,l) across the 16 lanes (tx) owning each row
    #pragma unroll
    for (int i = 0; i < 4; ++i) {
        float m = m_i[i], l = l_i[i];
        #pragma unroll
        for (int off = 1; off < 16; off <<= 1) {
            float mo = __shfl_xor(m, off, 64);
            float lo = __shfl_xor(l, off, 64);
            float mn = fmaxf(m, mo);
            l = l * __expf(m - mn) + lo * __expf(mo - mn);
            m = mn;
        }
        if (tx == 0) { mres[ty * 4 + i] = m; lrcp[ty * 4 + i] = 1.0f / l; }
    }

    // pass 2: normalize + AV
    float cacc[4][4] = {};
    for (int c = 0; c < 32; ++c) {
        __syncthreads();
        const float* vbase = vg + ((size_t)bh * 2048 + c * 64) * 64;
        #pragma unroll
        for (int r = 0; r < 4; ++r) {
            int s = tid + r * 256;
            int row = s >> 4, dc = (s & 15) * 4;
            float4 v = *(const float4*)&vbase[row * 64 + dc];
            *(float4*)&buf1[row * 68 + dc] = v;
        }
        #pragma unroll
        for (int i = 0; i < 4; ++i) {
            int qrow = ty * 4 + i;
            int qglob = qt0 + qrow;
            float4 sv = *(const float4*)&wbase[(size_t)qglob * 2048 + c * 64 + tx * 4];
            float m = mres[qrow], lr = lrcp[qrow];
            float4 wv;
            wv.x = __expf(sv.x - m) * lr;
            wv.y = __expf(sv.y - m) * lr;
            wv.z = __expf(sv.z - m) * lr;
            wv.w = __expf(sv.w - m) * lr;
            *(float4*)&wbase[(size_t)qglob * 2048 + c * 64 + tx * 4] = wv;
            buf2[qrow * 65 + tx * 4 + 0] = wv.x;
            buf2[qrow * 65 + tx * 4 + 1] = wv.y;
            buf2[qrow * 65 + tx * 4 + 2] = wv.z;
            buf2[qrow * 65 + tx * 4 + 3] = wv.w;
        }
        __syncthreads();
        #pragma unroll 8
        for (int kj = 0; kj < 64; ++kj) {
            float4 v4 = *(const float4*)&buf1[kj * 68 + tx * 4];
            float va[4] = {v4.x, v4.y, v4.z, v4.w};
            #pragma unroll
            for (int i = 0; i < 4; ++i) {
                float w = buf2[(ty * 4 + i) * 65 + kj];
                #pragma unroll
                for (int jj = 0; jj < 4; ++jj)
                    cacc[i][jj] += w * va[jj];
            }
        }
    }
    #pragma unroll
    for (int i = 0; i < 4; ++i) {
        int qglob = qt0 + ty * 4 + i;
        float4 r = make_float4(cacc[i][0], cacc[i][1], cacc[i][2], cacc[i][3]);
        *(float4*)&ctx[((size_t)(b * 2048 + qglob)) * 1024 + h * 64 + tx * 4] = r;
    }
}

__global__ __launch_bounds__(256)
void posbias_kernel(const float* __restrict__ rel_table, float* __restrict__ pb)
{
    size_t g = ((size_t)blockIdx.x * 256 + threadIdx.x) * 4;
    int k = (int)(g & 2047);
    int q = (int)((g >> 11) & 2047);
    int h = (int)(g >> 22);
    float4 r;
    float* rp = (float*)&r;
    #pragma unroll
    for (int j = 0; j < 4; ++j)
        rp[j] = rel_table[rel_bucket(k + j - q) * 16 + h];
    *(float4*)&pb[g] = r;
}

extern "C" void kernel_launch(void* const* d_in, const int* in_sizes, int n_in,
                              void* d_out, int out_size, void* d_ws, size_t ws_size,
                              hipStream_t stream) {
    const float* x    = (const float*)d_in[0];
    const float* Wq   = (const float*)d_in[1];
    const float* bq   = (const float*)d_in[2];
    const float* Wk   = (const float*)d_in[3];
    const float* bk   = (const float*)d_in[4];
    const float* Wv   = (const float*)d_in[5];
    const float* bv   = (const float*)d_in[6];
    const float* Wo   = (const float*)d_in[7];
    const float* bo   = (const float*)d_in[8];
    const float* rt   = (const float*)d_in[9];
    const int*   mask = (const int*)d_in[10];

    float* out = (float*)d_out;
    float* wts = out + W_OFF;
    float* pb  = out + PB_OFF;

    // Scratch lives in the pos_bias output region; pos_bias is filled LAST.
    float* qs  = pb;
    float* ks  = pb + 4194304;
    float* vs  = pb + 8388608;
    float* ctx = pb + 12582912;

    dim3 bb(256);
    dim3 gg(16, 64);
    gemm_4096_1024<<<gg, bb, 0, stream>>>(x, Wq, bq, qs, 1);
    gemm_4096_1024<<<gg, bb, 0, stream>>>(x, Wk, bk, ks, 1);
    gemm_4096_1024<<<gg, bb, 0, stream>>>(x, Wv, bv, vs, 1);
    attn_kernel<<<dim3(32, 32), bb, 0, stream>>>(qs, ks, vs, rt, mask, wts, ctx);
    gemm_4096_1024<<<gg, bb, 0, stream>>>(ctx, Wo, bo, out, 0);
    posbias_kernel<<<dim3(65536), bb, 0, stream>>>(rt, pb);
}

// Round 2
// 1155.555 us; speedup vs baseline: 1.6412x; 1.6412x over previous
//
#include <hip/hip_runtime.h>
#include <math.h>

typedef _Float16 f16;
typedef f16 f16x8 __attribute__((ext_vector_type(8)));
typedef f16 f16x4 __attribute__((ext_vector_type(4)));
typedef float f32x4 __attribute__((ext_vector_type(4)));

// d_out layout (float offsets): out | weights | pos_bias
#define W_OFF   (2*2048*1024)               // 4,194,304
#define PB_OFF  (W_OFF + 2LL*16*2048*2048)  // 138,412,032

#define NEG_BIG (-1.0e30f)

// T5 relative-position bucket, fp32 math ordered like the numpy reference.
__device__ __forceinline__ int rel_bucket(int rel) {
    int ret = rel > 0 ? 32 : 0;
    int n = rel < 0 ? -rel : rel;
    if (n < 16) return ret + n;
    float fn = (float)n;
    float t = logf(fn * (1.0f / 16.0f));
    t = t / 1.1394343f;                    // fp32(np.log(50/16))
    int large = 16 + (int)(t * 16.0f);
    if (large > 31) large = 31;
    return ret + large;
}

// ---------- small prep kernels ----------

__global__ __launch_bounds__(256)
void conv_f16_kernel(const float* __restrict__ in, f16* __restrict__ out) {
    size_t i = ((size_t)blockIdx.x * 256 + threadIdx.x) * 4;
    float4 v = *(const float4*)&in[i];
    f16x4 h = { (f16)v.x, (f16)v.y, (f16)v.z, (f16)v.w };
    *(f16x4*)&out[i] = h;
}

// W (1024x1024 fp32, [k][n]) -> Wt (fp16, [n][k])
__global__ __launch_bounds__(256)
void transpose_w_kernel(const float* __restrict__ W, f16* __restrict__ Wt) {
    __shared__ float tile[64 * 68];
    const int tid = threadIdx.x;
    const int bi = blockIdx.x, bj = blockIdx.y;  // bi: k-tile, bj: n-tile
    #pragma unroll
    for (int it = 0; it < 4; ++it) {
        int slot = tid + it * 256;               // 0..1023
        int row = slot >> 4, col4 = (slot & 15) * 4;
        float4 v = *(const float4*)&W[(size_t)(bi * 64 + row) * 1024 + bj * 64 + col4];
        *(float4*)&tile[row * 68 + col4] = v;
    }
    __syncthreads();
    #pragma unroll
    for (int it = 0; it < 4; ++it) {
        int slot = tid + it * 256;
        int nrow = slot >> 4, kcol4 = (slot & 15) * 4;
        f16x4 h;
        #pragma unroll
        for (int j = 0; j < 4; ++j)
            h[j] = (f16)tile[(kcol4 + j) * 68 + nrow];
        *(f16x4*)&Wt[(size_t)(bj * 64 + nrow) * 1024 + bi * 64 + kcol4] = h;
    }
}

// bias_delta table: tbl[h*4096 + dd] = rel_table[bucket(dd-2047)][h]
__global__ __launch_bounds__(256)
void bias_tbl_kernel(const float* __restrict__ rel_table, float* __restrict__ tbl) {
    int idx = blockIdx.x * 256 + threadIdx.x;   // 0..65535
    int h = idx >> 12, dd = idx & 4095;
    tbl[idx] = rel_table[rel_bucket(dd - 2047) * 16 + h];
}

// v (bh, s, d) fp16 -> vt (bh, d, s) fp16
__global__ __launch_bounds__(256)
void transpose_v_kernel(const f16* __restrict__ vh, f16* __restrict__ vt) {
    __shared__ f16 tile[64 * 72];
    const int tid = threadIdx.x;
    const int st = blockIdx.x, bh = blockIdx.y;
    #pragma unroll
    for (int it = 0; it < 2; ++it) {
        int slot = tid + it * 256;               // 0..511
        int row = slot >> 3, col8 = (slot & 7) * 8;
        f16x8 v = *(const f16x8*)&vh[((size_t)bh * 2048 + st * 64 + row) * 64 + col8];
        *(f16x8*)&tile[row * 72 + col8] = v;
    }
    __syncthreads();
    #pragma unroll
    for (int it = 0; it < 2; ++it) {
        int slot = tid + it * 256;
        int drow = slot >> 3, scol8 = (slot & 7) * 8;
        f16x8 r;
        #pragma unroll
        for (int j = 0; j < 8; ++j)
            r[j] = tile[(scol8 + j) * 72 + drow];
        *(f16x8*)&vt[((size_t)bh * 64 + drow) * 2048 + st * 64 + scol8] = r;
    }
}

// ---------- fp16 MFMA GEMM: C[4096x1024] = A[4096x1024] * Bt^T + bias ----------
// A row-major fp16, Bt = B^T row-major fp16 (N x K).
// mode 0: fp32 row-major out.  mode 1: fp16 (b,h,s,d) out.
__global__ __launch_bounds__(256)
void gemm_f16(const f16* __restrict__ A, const f16* __restrict__ Bt,
              const float* __restrict__ bias, void* __restrict__ Cout, int mode)
{
    __shared__ f16 aLDS[128 * 32];   // frag-linear: [mt(8)][lane(64)][8]
    __shared__ f16 bLDS[128 * 32];
    const int tid = threadIdx.x;
    const int lane = tid & 63, wv = tid >> 6;
    const int quad = lane >> 4, l15 = lane & 15;
    const int wm = (wv & 1) * 64, wn = (wv >> 1) * 64;
    const int bm = blockIdx.y * 128, bn = blockIdx.x * 128;

    f32x4 acc[4][4];
    #pragma unroll
    for (int i = 0; i < 4; ++i)
        #pragma unroll
        for (int j = 0; j < 4; ++j)
            acc[i][j] = (f32x4){0.f, 0.f, 0.f, 0.f};

    for (int k0 = 0; k0 < 1024; k0 += 32) {
        __syncthreads();
        #pragma unroll
        for (int s = 0; s < 2; ++s) {
            int slot = tid + s * 256;            // 0..511
            int mt = slot >> 6, ln = slot & 63;
            int row = mt * 16 + (ln & 15), kk = (ln >> 4) * 8;
            float4 va = *(const float4*)&A[(size_t)(bm + row) * 1024 + k0 + kk];
            *(float4*)&aLDS[slot * 8] = va;
            float4 vb = *(const float4*)&Bt[(size_t)(bn + row) * 1024 + k0 + kk];
            *(float4*)&bLDS[slot * 8] = vb;
        }
        __syncthreads();
        f16x8 af[4], bf[4];
        #pragma unroll
        for (int i = 0; i < 4; ++i) {
            af[i] = *(const f16x8*)&aLDS[(((wm >> 4) + i) * 64 + lane) * 8];
            bf[i] = *(const f16x8*)&bLDS[(((wn >> 4) + i) * 64 + lane) * 8];
        }
        #pragma unroll
        for (int i = 0; i < 4; ++i)
            #pragma unroll
            for (int j = 0; j < 4; ++j)
                acc[i][j] = __builtin_amdgcn_mfma_f32_16x16x32_f16(af[i], bf[j], acc[i][j], 0, 0, 0);
    }

    #pragma unroll
    for (int j = 0; j < 4; ++j) {
        int n = bn + wn + j * 16 + l15;
        float bz = bias[n];
        #pragma unroll
        for (int i = 0; i < 4; ++i) {
            #pragma unroll
            for (int r = 0; r < 4; ++r) {
                int m = bm + wm + i * 16 + quad * 4 + r;
                float val = acc[i][j][r] + bz;
                if (mode == 0) {
                    ((float*)Cout)[(size_t)m * 1024 + n] = val;
                } else {
                    int b = m >> 11, srow = m & 2047, h = n >> 6, d = n & 63;
                    ((f16*)Cout)[(((size_t)(b * 16 + h) * 2048 + srow) << 6) + d] = (f16)val;
                }
            }
        }
    }
}

// ---------- attention ----------
// Per block: one (bh, 64-query tile). Wave w owns q rows [qt0+16w, qt0+16w+16).
__global__ __launch_bounds__(256)
void attn_f16(const f16* __restrict__ qh, const f16* __restrict__ kh,
              const f16* __restrict__ vth, const float* __restrict__ tbl,
              const int* __restrict__ mask, float* __restrict__ wout,
              f16* __restrict__ ctxh)
{
    __shared__ float biasL[4096];        // 16 KB
    __shared__ float maskL[2048];        // 8 KB
    __shared__ f16 kL[8 * 64 * 8];       // 8 KB  [frag(dstep*4+nt)][lane][8]
    __shared__ f16 vL[8 * 64 * 8];       // 8 KB  [frag(ks*4+nt)][lane][8]
    __shared__ f16 wnat[4 * 16 * 88];    // 11 KB [wave][q16][key64, stride 88]

    const int tid = threadIdx.x, lane = tid & 63, wv = tid >> 6;
    const int quad = lane >> 4, l15 = lane & 15;
    const int bh = blockIdx.y, b = bh >> 4, h = bh & 15;
    const int qt0 = blockIdx.x * 64;

    for (int i = tid; i < 1024; i += 256)
        *(float4*)&biasL[i * 4] = *(const float4*)&tbl[h * 4096 + i * 4];
    for (int i = tid; i < 512; i += 256) {
        int4 mv = *(const int4*)&mask[b * 2048 + i * 4];
        float4 f;
        f.x = mv.x ? NEG_BIG : 0.f;  f.y = mv.y ? NEG_BIG : 0.f;
        f.z = mv.z ? NEG_BIG : 0.f;  f.w = mv.w ? NEG_BIG : 0.f;
        *(float4*)&maskL[i * 4] = f;
    }

    const int q0 = qt0 + wv * 16;
    f16x8 aq[2];
    #pragma unroll
    for (int ds = 0; ds < 2; ++ds)
        aq[ds] = *(const f16x8*)&qh[((size_t)bh * 2048 + q0 + l15) * 64 + ds * 32 + quad * 8];
    __syncthreads();

    const int qrow_base = q0 + quad * 4;
    float lI[4] = {0.f, 0.f, 0.f, 0.f};

    // ---- pass A: l[r] = sum_k exp(s - 20) ----
    for (int c = 0; c < 32; ++c) {
        __syncthreads();
        #pragma unroll
        for (int s = 0; s < 2; ++s) {
            int slot = tid + s * 256;
            int f = slot >> 6, ln = slot & 63;
            int dstep = f >> 2, nt = f & 3;
            int key = nt * 16 + (ln & 15);
            float4 v = *(const float4*)&kh[((size_t)bh * 2048 + c * 64 + key) * 64 + dstep * 32 + (ln >> 4) * 8];
            *(float4*)&kL[slot * 8] = v;
        }
        __syncthreads();
        #pragma unroll
        for (int nt = 0; nt < 4; ++nt) {
            f32x4 s4 = (f32x4){0.f, 0.f, 0.f, 0.f};
            #pragma unroll
            for (int ds = 0; ds < 2; ++ds) {
                f16x8 bf = *(const f16x8*)&kL[((ds * 4 + nt) * 64 + lane) * 8];
                s4 = __builtin_amdgcn_mfma_f32_16x16x32_f16(aq[ds], bf, s4, 0, 0, 0);
            }
            int k = c * 64 + nt * 16 + l15;
            float mk = maskL[k];
            #pragma unroll
            for (int r = 0; r < 4; ++r) {
                int q = qrow_base + r;
                float sc = s4[r] + biasL[k - q + 2047] + mk;
                lI[r] += __expf(sc - 20.f);
            }
        }
    }
    #pragma unroll
    for (int r = 0; r < 4; ++r) {
        float l = lI[r];
        l += __shfl_xor(l, 1, 64);
        l += __shfl_xor(l, 2, 64);
        l += __shfl_xor(l, 4, 64);
        l += __shfl_xor(l, 8, 64);
        lI[r] = 1.0f / l;
    }

    // ---- pass B: recompute scores, write weights, accumulate O = W*V ----
    float* wbase = wout + (size_t)bh * 2048 * 2048;
    f32x4 oacc[4];
    #pragma unroll
    for (int nt = 0; nt < 4; ++nt) oacc[nt] = (f32x4){0.f, 0.f, 0.f, 0.f};

    for (int c = 0; c < 32; ++c) {
        __syncthreads();
        #pragma unroll
        for (int s = 0; s < 2; ++s) {
            int slot = tid + s * 256;
            int f = slot >> 6, ln = slot & 63;
            {
                int dstep = f >> 2, nt = f & 3;
                int key = nt * 16 + (ln & 15);
                float4 v = *(const float4*)&kh[((size_t)bh * 2048 + c * 64 + key) * 64 + dstep * 32 + (ln >> 4) * 8];
                *(float4*)&kL[slot * 8] = v;
            }
            {
                int ks = f >> 2, nt = f & 3;
                int d = nt * 16 + (ln & 15);
                float4 v = *(const float4*)&vth[((size_t)bh * 64 + d) * 2048 + c * 64 + ks * 32 + (ln >> 4) * 8];
                *(float4*)&vL[slot * 8] = v;
            }
        }
        __syncthreads();

        #pragma unroll
        for (int nt = 0; nt < 4; ++nt) {
            f32x4 s4 = (f32x4){0.f, 0.f, 0.f, 0.f};
            #pragma unroll
            for (int ds = 0; ds < 2; ++ds) {
                f16x8 bf = *(const f16x8*)&kL[((ds * 4 + nt) * 64 + lane) * 8];
                s4 = __builtin_amdgcn_mfma_f32_16x16x32_f16(aq[ds], bf, s4, 0, 0, 0);
            }
            int k = c * 64 + nt * 16 + l15;
            float mk = maskL[k];
            int key64 = nt * 16 + l15;
            #pragma unroll
            for (int r = 0; r < 4; ++r) {
                int q = qrow_base + r;
                float sc = s4[r] + biasL[k - q + 2047] + mk;
                float w = __expf(sc - 20.f) * lI[r];
                wbase[(size_t)q * 2048 + k] = w;
                wnat[wv * 1408 + (quad * 4 + r) * 88 + key64] = (f16)w;
            }
        }
        // per-wave LDS RAW on wnat: compiler-inserted lgkmcnt; no barrier needed
        #pragma unroll
        for (int ks = 0; ks < 2; ++ks) {
            f16x8 wf = *(const f16x8*)&wnat[wv * 1408 + l15 * 88 + ks * 32 + quad * 8];
            #pragma unroll
            for (int nt = 0; nt < 4; ++nt) {
                f16x8 vf = *(const f16x8*)&vL[((ks * 4 + nt) * 64 + lane) * 8];
                oacc[nt] = __builtin_amdgcn_mfma_f32_16x16x32_f16(wf, vf, oacc[nt], 0, 0, 0);
            }
        }
    }

    #pragma unroll
    for (int nt = 0; nt < 4; ++nt) {
        int d = nt * 16 + l15;
        #pragma unroll
        for (int r = 0; r < 4; ++r) {
            int q = qrow_base + r;
            ctxh[((size_t)(b * 2048) + q) * 1024 + h * 64 + d] = (f16)oacc[nt][r];
        }
    }
}

// ---------- pos_bias (identical math to round 1; runs last over scratch) ----------
__global__ __launch_bounds__(256)
void posbias_kernel(const float* __restrict__ rel_table, float* __restrict__ pb)
{
    size_t g = ((size_t)blockIdx.x * 256 + threadIdx.x) * 4;
    int k = (int)(g & 2047);
    int q = (int)((g >> 11) & 2047);
    int h = (int)(g >> 22);
    float4 r;
    float* rp = (float*)&r;
    #pragma unroll
    for (int j = 0; j < 4; ++j)
        rp[j] = rel_table[rel_bucket(k + j - q) * 16 + h];
    *(float4*)&pb[g] = r;
}

extern "C" void kernel_launch(void* const* d_in, const int* in_sizes, int n_in,
                              void* d_out, int out_size, void* d_ws, size_t ws_size,
                              hipStream_t stream) {
    const float* x    = (const float*)d_in[0];
    const float* Wq   = (const float*)d_in[1];
    const float* bq   = (const float*)d_in[2];
    const float* Wk   = (const float*)d_in[3];
    const float* bk   = (const float*)d_in[4];
    const float* Wv   = (const float*)d_in[5];
    const float* bv   = (const float*)d_in[6];
    const float* Wo   = (const float*)d_in[7];
    const float* bo   = (const float*)d_in[8];
    const float* rt   = (const float*)d_in[9];
    const int*   mask = (const int*)d_in[10];

    float* out = (float*)d_out;
    float* wts = out + W_OFF;
    float* pb  = out + PB_OFF;

    // Scratch in the pos_bias region (67.1M floats); pos_bias written LAST.
    float* tbl  = pb;                         // 65,536 floats
    f16*   xh   = (f16*)(pb + 65536);         // 4,194,304 halfs
    f16*   wqt  = (f16*)(pb + 2162688);       // 1,048,576 halfs each
    f16*   wkt  = (f16*)(pb + 2686976);
    f16*   wvt  = (f16*)(pb + 3211264);
    f16*   wot  = (f16*)(pb + 3735552);
    f16*   qh   = (f16*)(pb + 4259840);       // 4,194,304 halfs each
    f16*   kh   = (f16*)(pb + 6356992);
    f16*   vh   = (f16*)(pb + 8454144);
    f16*   vth  = (f16*)(pb + 10551296);
    f16*   ctxh = (f16*)(pb + 12648448);

    dim3 blk(256);
    conv_f16_kernel<<<dim3(4096), blk, 0, stream>>>(x, xh);
    transpose_w_kernel<<<dim3(16, 16), blk, 0, stream>>>(Wq, wqt);
    transpose_w_kernel<<<dim3(16, 16), blk, 0, stream>>>(Wk, wkt);
    transpose_w_kernel<<<dim3(16, 16), blk, 0, stream>>>(Wv, wvt);
    transpose_w_kernel<<<dim3(16, 16), blk, 0, stream>>>(Wo, wot);
    bias_tbl_kernel<<<dim3(256), blk, 0, stream>>>(rt, tbl);

    gemm_f16<<<dim3(8, 32), blk, 0, stream>>>(xh, wqt, bq, qh, 1);
    gemm_f16<<<dim3(8, 32), blk, 0, stream>>>(xh, wkt, bk, kh, 1);
    gemm_f16<<<dim3(8, 32), blk, 0, stream>>>(xh, wvt, bv, vh, 1);
    transpose_v_kernel<<<dim3(32, 32), blk, 0, stream>>>(vh, vth);

    attn_f16<<<dim3(32, 32), blk, 0, stream>>>(qh, kh, vth, tbl, mask, wts, ctxh);

    gemm_f16<<<dim3(8, 32), blk, 0, stream>>>(ctxh, wot, bo, out, 0);
    posbias_kernel<<<dim3(65536), blk, 0, stream>>>(rt, pb);
}